// Round 1
// 1958.097 us; speedup vs baseline: 1.1970x; 1.1970x over previous
//
#include <hip/hip_runtime.h>

// Problem constants (from reference): T=8, D=512, H=100, C=2, NEG=1
constexpr int D_ = 512;
constexpr int H_ = 100;
constexpr int C_ = 2;
constexpr int T_ = 8;

constexpr int TE = 64;          // edges per block in main kernel
constexpr int DC = 32;          // D-chunk (floats) staged in LDS
constexpr int NC = D_ / DC;     // 16 chunks
constexpr int SB = 128;         // sort segments / blocks
constexpr int STH = 256;        // threads per sort block

// ws layout (ints): [0:8) typeBase | [8:16) typeCount | [16:25) tileBase
//                   [32:32+SB*8) hist/blockBase | [1056 : 1056+E) sorted_e
constexpr int WS_HIST = 32;
constexpr int WS_SORTED = 32 + SB * T_;   // 1056

__device__ __forceinline__ int swz(int r) { return (r ^ (r >> 3)) & 7; }

// ---------------------------------------------------------------------------
// K1: per-segment histogram. SB blocks x STH threads.
// ---------------------------------------------------------------------------
__global__ __launch_bounds__(STH) void k_hist(const int* __restrict__ et, int E, int seg,
                                              int* __restrict__ hist) {
    __shared__ int hb[T_];
    const int b = blockIdx.x, tid = threadIdx.x;
    if (tid < T_) hb[tid] = 0;
    __syncthreads();
    const int segLo = b * seg;
    const int segHi = min(E, segLo + seg);
    const int per = (seg + STH - 1) / STH;
    const int lo = segLo + tid * per;
    const int hi = min(segHi, lo + per);
    int c[T_];
#pragma unroll
    for (int j = 0; j < T_; ++j) c[j] = 0;
    for (int i = lo; i < hi; ++i) {
        int ty = et[i];
#pragma unroll
        for (int j = 0; j < T_; ++j) c[j] += (ty == j) ? 1 : 0;
    }
#pragma unroll
    for (int j = 0; j < T_; ++j)
        if (c[j]) atomicAdd(&hb[j], c[j]);
    __syncthreads();
    if (tid < T_) hist[b * T_ + tid] = hb[tid];
}

// ---------------------------------------------------------------------------
// K2: scan over SB segment histograms (one block of SB threads).
// Produces typeBase/typeCount/tileBase and rewrites hist -> blockBase[b][t].
// ---------------------------------------------------------------------------
__global__ __launch_bounds__(SB) void k_scan(int* __restrict__ hist,
                                             int* __restrict__ typeBase,
                                             int* __restrict__ typeCount,
                                             int* __restrict__ tileBase) {
    __shared__ int sc[SB][T_ + 1];   // stride 9 -> conflict-free
    __shared__ int sbase[T_];
    const int tid = threadIdx.x;
#pragma unroll
    for (int j = 0; j < T_; ++j) sc[tid][j] = hist[tid * T_ + j];
    __syncthreads();
    for (int ofs = 1; ofs < SB; ofs <<= 1) {
        int v[T_];
        if (tid >= ofs) {
#pragma unroll
            for (int j = 0; j < T_; ++j) v[j] = sc[tid - ofs][j];
        }
        __syncthreads();
        if (tid >= ofs) {
#pragma unroll
            for (int j = 0; j < T_; ++j) sc[tid][j] += v[j];
        }
        __syncthreads();
    }
    if (tid == 0) {
        int b = 0, tb = 0;
#pragma unroll
        for (int j = 0; j < T_; ++j) {
            int cntj = sc[SB - 1][j];
            sbase[j] = b;
            typeBase[j] = b;
            typeCount[j] = cntj;
            tileBase[j] = tb;
            b += cntj;
            tb += (cntj + TE - 1) / TE;
        }
        tileBase[T_] = tb;
    }
    __syncthreads();
#pragma unroll
    for (int j = 0; j < T_; ++j)
        hist[tid * T_ + j] = sbase[j] + (tid ? sc[tid - 1][j] : 0);
}

// ---------------------------------------------------------------------------
// K3: stable scatter. SB blocks x STH threads, same segmentation as K1.
// ---------------------------------------------------------------------------
__global__ __launch_bounds__(STH) void k_scatter(const int* __restrict__ et, int E, int seg,
                                                 const int* __restrict__ blockBase,
                                                 int* __restrict__ sorted_e) {
    __shared__ int sc[STH][T_ + 1];
    const int b = blockIdx.x, tid = threadIdx.x;
    const int segLo = b * seg;
    const int segHi = min(E, segLo + seg);
    const int per = (seg + STH - 1) / STH;
    const int lo = segLo + tid * per;
    const int hi = min(segHi, lo + per);
    int c[T_];
#pragma unroll
    for (int j = 0; j < T_; ++j) c[j] = 0;
    for (int i = lo; i < hi; ++i) {
        int ty = et[i];
#pragma unroll
        for (int j = 0; j < T_; ++j) c[j] += (ty == j) ? 1 : 0;
    }
#pragma unroll
    for (int j = 0; j < T_; ++j) sc[tid][j] = c[j];
    __syncthreads();
    for (int ofs = 1; ofs < STH; ofs <<= 1) {
        int v[T_];
        if (tid >= ofs) {
#pragma unroll
            for (int j = 0; j < T_; ++j) v[j] = sc[tid - ofs][j];
        }
        __syncthreads();
        if (tid >= ofs) {
#pragma unroll
            for (int j = 0; j < T_; ++j) sc[tid][j] += v[j];
        }
        __syncthreads();
    }
    int p[T_];
#pragma unroll
    for (int j = 0; j < T_; ++j)
        p[j] = blockBase[b * T_ + j] + (tid ? sc[tid - 1][j] : 0);
    for (int i = lo; i < hi; ++i) {
        int ty = et[i];
        int r = 0;
#pragma unroll
        for (int j = 0; j < T_; ++j) {
            if (ty == j) { r = p[j]; p[j] = r + 1; }
        }
        sorted_e[r] = i;
    }
}

// ---------------------------------------------------------------------------
// Main fused kernel. Compact 1D grid: block b -> (type t, tile) via tileBase.
// Double-buffered async global_load_lds staging (linear LDS dest, source-side
// XOR column swizzle so compute-side ds_read_b128 is bank-conflict-free).
// h_save fused via LDS readback of the wave's own linear slots.
// ---------------------------------------------------------------------------
__global__ __launch_bounds__(256) void k_main(
    const float* __restrict__ h,
    const float* __restrict__ srcW, const float* __restrict__ srcB,
    const float* __restrict__ dstW, const float* __restrict__ dstB,
    const float* __restrict__ outW, const float* __restrict__ outB,
    const int* __restrict__ sorted_e,
    const int* __restrict__ typeBase, const int* __restrict__ typeCount,
    const int* __restrict__ tileBase,
    float* __restrict__ out, int E)
{
    const int b = blockIdx.x;
    if (b >= tileBase[T_]) return;
    int t = 0;
#pragma unroll
    for (int j = 1; j < T_; ++j) t += (b >= tileBase[j]) ? 1 : 0;
    const int i0   = (b - tileBase[t]) * TE;
    const int cnt  = typeCount[t];
    const int base = typeBase[t];
    const int tid = threadIdx.x;
    const int tx  = tid & 15;
    const int ty  = tid >> 4;

    __shared__ __align__(16) union {
        float4 stage[2][3 * TE * (DC / 4)];   // [buf][m*512 + r*8 + s], 49152 B
        float  edge[2][TE][H_ + 1];           // 51712 B (pad 101 -> conflict-free)
    } sh;
    __shared__ int eIdx[TE];

    if (tid < TE) {
        int p = i0 + tid;
        eIdx[tid] = sorted_e[base + (p < cnt ? p : i0)];  // clamp pads to a valid edge
    }
    __syncthreads();

    // staging geometry: flat float4 index f = tid + 256*ii -> (m = ii>>1,
    // r = (tid>>3) + 32*(ii&1), s = tid&7). Source column c4 = s ^ swz(r).
    const int s8 = tid & 7;
    const int r0 = tid >> 3;
    const int r1 = r0 + 32;
    const bool g0 = (i0 + r0) < cnt;
    const bool g1 = (i0 + r1) < cnt;
    const float* gsrc[6];
    {
        const int e0 = eIdx[r0], e1 = eIdx[r1];
        const int c40 = s8 ^ swz(r0);
        const int c41 = s8 ^ swz(r1);
#pragma unroll
        for (int ii = 0; ii < 6; ++ii) {
            int m  = ii >> 1;
            int e  = (ii & 1) ? e1 : e0;
            int c4 = (ii & 1) ? c41 : c40;
            gsrc[ii] = h + ((size_t)m * E + e) * D_ + (c4 << 2);
        }
    }
    float* const outH = out + (size_t)4 * E;        // h_save region
    const ptrdiff_t hsOfs = outH - h;               // uniform offset h -> h_save

    float4* const st0 = &sh.stage[0][0];
    float4* const st1 = &sh.stage[1][0];

    auto stage_issue = [&](float4* dstF4, int d0c) {
#pragma unroll
        for (int ii = 0; ii < 6; ++ii) {
            __builtin_amdgcn_global_load_lds(
                (const __attribute__((address_space(1))) void*)(gsrc[ii] + d0c),
                (__attribute__((address_space(3))) void*)(dstF4 + tid + ii * 256),
                16, 0, 0);
        }
    };

    float accS[4][7], accP[4][7], accN[4][7];
#pragma unroll
    for (int kk = 0; kk < 4; ++kk)
#pragma unroll
        for (int jj = 0; jj < 7; ++jj) { accS[kk][jj] = 0.f; accP[kk][jj] = 0.f; accN[kk][jj] = 0.f; }

    int jcs[7];
#pragma unroll
    for (int jj = 0; jj < 7; ++jj) {
        int j = jj * 16 + tx;
        jcs[jj] = (j < H_) ? j : (H_ - 1);   // clamp; clamped result unused
    }

    int rB[4], swk[4];
#pragma unroll
    for (int kk = 0; kk < 4; ++kk) {
        int r = ty * 4 + kk;
        rB[kk]  = r * 8;
        swk[kk] = swz(r);
    }

    const float* wsBase = srcW + (size_t)t * D_ * H_;
    const float* wdBase = dstW + (size_t)t * D_ * H_;

    stage_issue(st0, 0);   // prologue: chunk 0

    for (int ch = 0; ch < NC; ++ch) {
        float4* const cs = (ch & 1) ? st1 : st0;
        float4* const ns = (ch & 1) ? st0 : st1;
        const int d0 = ch * DC;

        // chunk-ch loads were issued one full compute phase ago -> drain ~free
        __syncthreads();

        if (ch + 1 < NC) stage_issue(ns, d0 + DC);   // prefetch next chunk

        // fused h_save: read own linear slots (conflict-free), mirror-store
#pragma unroll
        for (int ii = 0; ii < 4; ++ii) {
            float4 v = cs[tid + ii * 256];
            if ((ii & 1) ? g1 : g0)
                *(float4*)(const_cast<float*>(gsrc[ii]) + hsOfs + d0) = v;
        }

        const float* pws = wsBase + (size_t)d0 * H_;
        const float* pwd = wdBase + (size_t)d0 * H_;
#pragma unroll 1
        for (int dd4 = 0; dd4 < DC / 4; ++dd4) {
            float4 Av[3][4];
#pragma unroll
            for (int m = 0; m < 3; ++m)
#pragma unroll
                for (int kk = 0; kk < 4; ++kk)
                    Av[m][kk] = cs[m * 512 + rB[kk] + (dd4 ^ swk[kk])];

#pragma unroll
            for (int q = 0; q < 4; ++q) {
                const float* pws2 = pws + (size_t)(dd4 * 4 + q) * H_;
                const float* pwd2 = pwd + (size_t)(dd4 * 4 + q) * H_;
                float wsv[7], wdv[7];
#pragma unroll
                for (int jj = 0; jj < 7; ++jj) {
                    wsv[jj] = pws2[jcs[jj]];
                    wdv[jj] = pwd2[jcs[jj]];
                }
#pragma unroll
                for (int kk = 0; kk < 4; ++kk) {
                    float as = ((const float*)&Av[0][kk])[q];
                    float ap = ((const float*)&Av[1][kk])[q];
                    float an = ((const float*)&Av[2][kk])[q];
#pragma unroll
                    for (int jj = 0; jj < 7; ++jj) {
                        accS[kk][jj] = fmaf(as, wsv[jj], accS[kk][jj]);
                        accP[kk][jj] = fmaf(ap, wdv[jj], accP[kk][jj]);
                        accN[kk][jj] = fmaf(an, wdv[jj], accN[kk][jj]);
                    }
                }
            }
        }
    }

    __syncthreads();   // done with stage buffers; reuse union as edge buffer

    // bias + relu-combine into LDS
#pragma unroll
    for (int kk = 0; kk < 4; ++kk) {
        int k = ty * 4 + kk;
#pragma unroll
        for (int jj = 0; jj < 7; ++jj) {
            int j = jj * 16 + tx;
            if (j < H_) {
                float sb = srcB[t * H_ + j];
                float db = dstB[t * H_ + j];
                float s  = accS[kk][jj] + sb;
                float pz = accP[kk][jj] + db;
                float nz = accN[kk][jj] + db;
                sh.edge[0][k][j] = fmaxf(s + pz, 0.f);
                sh.edge[1][k][j] = fmaxf(s + nz, 0.f);
            }
        }
    }
    __syncthreads();

    // out layer: 256 threads -> (pn, c, k); dot over H=100, scatter to sorted pos
    {
        int pn = tid >> 7;
        int c  = (tid >> 6) & 1;
        int k  = tid & 63;
        if (i0 + k < cnt) {
            float acc = outB[t * C_ + c];
            const float* wo = outW + (size_t)t * H_ * C_ + c;
            const float* ev = &sh.edge[pn][k][0];
#pragma unroll 4
            for (int j = 0; j < H_; ++j) acc += ev[j] * wo[(size_t)j * C_];
            size_t pidx = (size_t)(base + i0 + k) * C_ + c;
            out[(pn ? (size_t)C_ * E : (size_t)0) + pidx] = acc;
        }
    }
}

// ---------------------------------------------------------------------------
extern "C" void kernel_launch(void* const* d_in, const int* in_sizes, int n_in,
                              void* d_out, int out_size, void* d_ws, size_t ws_size,
                              hipStream_t stream) {
    (void)n_in; (void)out_size; (void)ws_size;
    const float* h    = (const float*)d_in[0];
    const float* srcW = (const float*)d_in[1];
    const float* srcB = (const float*)d_in[2];
    const float* dstW = (const float*)d_in[3];
    const float* dstB = (const float*)d_in[4];
    const float* outW = (const float*)d_in[5];
    const float* outB = (const float*)d_in[6];
    const int*   et   = (const int*)d_in[7];
    const int E = in_sizes[7];

    float* out = (float*)d_out;
    int* ws = (int*)d_ws;
    int* typeBase  = ws;
    int* typeCount = ws + 8;
    int* tileBase  = ws + 16;
    int* hist      = ws + WS_HIST;
    int* sorted_e  = ws + WS_SORTED;

    const int seg = (E + SB - 1) / SB;
    k_hist<<<SB, STH, 0, stream>>>(et, E, seg, hist);
    k_scan<<<1, SB, 0, stream>>>(hist, typeBase, typeCount, tileBase);
    k_scatter<<<SB, STH, 0, stream>>>(et, E, seg, hist, sorted_e);

    const int maxTiles = (E + TE - 1) / TE + T_;   // >= sum of per-type ceil tiles
    k_main<<<maxTiles, 256, 0, stream>>>(h, srcW, srcB, dstW, dstB, outW, outB,
                                         sorted_e, typeBase, typeCount, tileBase,
                                         out, E);
}